// Round 31
// baseline (109.862 us; speedup 1.0000x reference)
//
#include <hip/hip_runtime.h>
#include <hip/hip_bf16.h>
#include <math.h>

#define B_   2
#define L_   512
#define DM   1024
#define DIP  4352
#define DPROJ 4224        // bf16 proj row stride (Z,X,BP,CP only)
#define DI   2048
#define NH_  32
#define HD   64
#define DS   64
#define NA   32
#define BL   (B_ * L_)
#define CHK  16
#define NCH  32
#define PB   (BL * 128)   // one skinny partial plane

// proj slice offsets (within DPROJ-stride bf16 buffer)
#define OFF_Z    0
#define OFF_X    2048
#define OFF_BP   4096
#define OFF_CP   4160

typedef short bf16x8s __attribute__((ext_vector_type(8)));
typedef float f32x4 __attribute__((ext_vector_type(4)));

// async global->LDS, 16B/lane; LDS dest is wave-uniform base + lane*16 (HW).
#define GL2LDS(gp, lp) __builtin_amdgcn_global_load_lds( \
    (const __attribute__((address_space(1))) unsigned int*)(const void*)(gp), \
    (__attribute__((address_space(3))) unsigned int*)(void*)(lp), 16, 0, 0)

__device__ __forceinline__ float softplusf(float x) {
    return x > 0.f ? x + log1pf(expf(-x)) : log1pf(expf(x));
}
__device__ __forceinline__ float sigmoidf_(float x) {
    return 1.f / (1.f + expf(-x));
}
__device__ __forceinline__ float wave_sum(float v) {
#pragma unroll
    for (int off = 32; off; off >>= 1) v += __shfl_xor(v, off);
    return v;
}
__device__ __forceinline__ ushort f2bf(float f) {
    uint u = __float_as_uint(f);
    return (ushort)((u + 0x7fffu + ((u >> 16) & 1u)) >> 16);
}
__device__ __forceinline__ float bf2f(ushort v) {
    return __uint_as_float((uint)v << 16);
}
__device__ __forceinline__ float4 ld_bf4(const ushort* p) {
    uint2 v = *(const uint2*)p;
    float4 r;
    r.x = __uint_as_float(v.x << 16);
    r.y = __uint_as_float(v.x & 0xffff0000u);
    r.z = __uint_as_float(v.y << 16);
    r.w = __uint_as_float(v.y & 0xffff0000u);
    return r;
}
__device__ __forceinline__ void st_bf4(ushort* p, float4 f) {
    uint2 v;
    v.x = (uint)f2bf(f.x) | ((uint)f2bf(f.y) << 16);
    v.y = (uint)f2bf(f.z) | ((uint)f2bf(f.w) << 16);
    *(uint2*)p = v;
}

// ---------------- fused prep: W transposes + u cast + skinny split-K --------
__global__ __launch_bounds__(256) void prep_all(const float* __restrict__ u,
                                                const float* __restrict__ W_in,
                                                const float* __restrict__ W_out,
                                                ushort* __restrict__ ubf,
                                                ushort* __restrict__ WinT,
                                                ushort* __restrict__ WoutT,
                                                float* __restrict__ pbuf) {
    __shared__ float smem[2560];      // 10 KB, reinterpreted per role
    const int blk = blockIdx.x;
    const int tid = threadIdx.x;

    if (blk < 1600) {                 // ---- transpose roles ----
        ushort (*t2)[72] = (ushort(*)[72])smem;   // [64][72] = 9216 B
        const float* in;
        ushort* outp;
        int R, C, c0, r0;
        if (blk < 1088) {
            in = W_in; outp = WinT; R = DM; C = DIP;
            c0 = (blk % 68) * 64; r0 = (blk / 68) * 64;
        } else {
            const int bi = blk - 1088;
            in = W_out; outp = WoutT; R = DI; C = DM;
            c0 = (bi % 16) * 64; r0 = (bi / 16) * 64;
        }
        const int cq = tid & 15;
        const int rrb = tid >> 4;
#pragma unroll
        for (int j = 0; j < 4; ++j) {
            const int rr = j * 16 + rrb;
            float4 v = *(const float4*)&in[(size_t)(r0 + rr) * C + c0 + cq * 4];
            uint u0 = (uint)f2bf(v.x) | ((uint)f2bf(v.y) << 16);
            uint u1 = (uint)f2bf(v.z) | ((uint)f2bf(v.w) << 16);
            const int g = cq ^ ((rr >> 3) & 3);
            *(uint2*)&t2[rr][g * 4] = make_uint2(u0, u1);
        }
        __syncthreads();
        const int rq = tid & 7;
        const int ccb = tid >> 3;
#pragma unroll
        for (int j = 0; j < 2; ++j) {
            const int cc = j * 32 + ccb;
            ushort a[8];
#pragma unroll
            for (int i = 0; i < 8; ++i) {
                const int r = rq * 8 + i;
                const int g = (cc >> 2) ^ ((r >> 3) & 3);
                a[i] = t2[r][g * 4 + (cc & 3)];
            }
            uint4 w;
            w.x = (uint)a[0] | ((uint)a[1] << 16);
            w.y = (uint)a[2] | ((uint)a[3] << 16);
            w.z = (uint)a[4] | ((uint)a[5] << 16);
            w.w = (uint)a[6] | ((uint)a[7] << 16);
            *(uint4*)&outp[(size_t)(c0 + cc) * R + r0 + rq * 8] = w;
        }
        return;
    }
    if (blk < 2624) {                 // ---- u cast role ----
        const int i = (blk - 1600) * 256 + tid;
        float4 v = ((const float4*)u)[i];
        uint u0 = (uint)f2bf(v.x) | ((uint)f2bf(v.y) << 16);
        uint u1 = (uint)f2bf(v.z) | ((uint)f2bf(v.w) << 16);
        *(uint2*)&ubf[(size_t)i * 4] = make_uint2(u0, u1);
        return;
    }
    // ---- skinny split-K role ----
    float (*us)[256] = (float(*)[256])smem;       // 4 x 256 f = 4 KB
    float* part = smem + 1024;                    // 4 x 256 f = 4 KB
    const int sblk = blk - 2624;
    const int rb = sblk & 255;
    const int ks = sblk >> 8;
    const int blr = rb * 4;
    const int k0 = ks * 256;
    {
        const int r = tid >> 6, s = tid & 63;
        *(float4*)&us[r][s * 4] = *(const float4*)&u[(size_t)(blr + r) * DM + k0 + s * 4];
    }
    __syncthreads();
    const int col = tid & 127;
    const int half = tid >> 7;
    float s0 = 0.f, s1 = 0.f, s2 = 0.f, s3 = 0.f;
    const float* wp = W_in + (size_t)(k0 + half * 128) * DIP + 4224 + col;
#pragma unroll 16
    for (int k = 0; k < 128; ++k) {
        const float wv = wp[(size_t)k * DIP];
        s0 = fmaf(us[0][half * 128 + k], wv, s0);
        s1 = fmaf(us[1][half * 128 + k], wv, s1);
        s2 = fmaf(us[2][half * 128 + k], wv, s2);
        s3 = fmaf(us[3][half * 128 + k], wv, s3);
    }
    part[0 * 256 + tid] = s0; part[1 * 256 + tid] = s1;
    part[2 * 256 + tid] = s2; part[3 * 256 + tid] = s3;
    __syncthreads();
    if (tid < 128) {
#pragma unroll
        for (int r = 0; r < 4; ++r)
            pbuf[((size_t)ks * BL + blr + r) * 128 + tid] =
                part[r * 256 + tid] + part[r * 256 + 128 + tid];
    }
}

// ---------------- bf16 MFMA GEMM: C[M,N] = A[M,K] @ BT[N,K] -----------------
__global__ __launch_bounds__(256) void gemm_bf16(const ushort* __restrict__ A,
                                                 const ushort* __restrict__ BT,
                                                 float* __restrict__ C,
                                                 int K, int ldc, int kslice,
                                                 size_t partStride, int bf16out) {
    __shared__ ushort sA[2][64 * 64];     // 2 x 8 KB
    __shared__ ushort sB[2][128 * 64];    // 2 x 16 KB
    const int tid = threadIdx.x;
    const int l = tid & 63;
    const int wv = tid >> 6;
    const int wr = wv >> 1, wc = wv & 1;
    const int brow = blockIdx.y * 64;
    const int bcol = blockIdx.x * 128;
    const int kstart = blockIdx.z * kslice;
    float* Cp = C + (size_t)blockIdx.z * partStride;

    const int rr8 = l >> 3;           // 0..7
    const int swz = ((l & 7) ^ rr8) * 8;   // pre-swizzled source slot (ushort)

    const ushort* gA0 = A + (size_t)(brow + wv * 16 + 0 + rr8) * K + kstart + swz;
    const ushort* gA1 = A + (size_t)(brow + wv * 16 + 8 + rr8) * K + kstart + swz;
    const ushort* gB0 = BT + (size_t)(bcol + wv * 32 + 0 + rr8) * K + kstart + swz;
    const ushort* gB1 = BT + (size_t)(bcol + wv * 32 + 8 + rr8) * K + kstart + swz;
    const ushort* gB2 = BT + (size_t)(bcol + wv * 32 + 16 + rr8) * K + kstart + swz;
    const ushort* gB3 = BT + (size_t)(bcol + wv * 32 + 24 + rr8) * K + kstart + swz;

    f32x4 acc[2][4] = {};

    GL2LDS(gA0, &sA[0][(wv * 16 + 0) * 64]);
    GL2LDS(gA1, &sA[0][(wv * 16 + 8) * 64]);
    GL2LDS(gB0, &sB[0][(wv * 32 + 0) * 64]);
    GL2LDS(gB1, &sB[0][(wv * 32 + 8) * 64]);
    GL2LDS(gB2, &sB[0][(wv * 32 + 16) * 64]);
    GL2LDS(gB3, &sB[0][(wv * 32 + 24) * 64]);
    __syncthreads();

    for (int k0 = 0; k0 < kslice; k0 += 64) {
        const int cur = (k0 >> 6) & 1;
        const int nxt = cur ^ 1;
        if (k0 + 64 < kslice) {
            GL2LDS(gA0 + k0 + 64, &sA[nxt][(wv * 16 + 0) * 64]);
            GL2LDS(gA1 + k0 + 64, &sA[nxt][(wv * 16 + 8) * 64]);
            GL2LDS(gB0 + k0 + 64, &sB[nxt][(wv * 32 + 0) * 64]);
            GL2LDS(gB1 + k0 + 64, &sB[nxt][(wv * 32 + 8) * 64]);
            GL2LDS(gB2 + k0 + 64, &sB[nxt][(wv * 32 + 16) * 64]);
            GL2LDS(gB3 + k0 + 64, &sB[nxt][(wv * 32 + 24) * 64]);
        }
        bf16x8s af[2][2], bfr[4][2];
#pragma unroll
        for (int m = 0; m < 2; ++m) {
            const int row = wr * 32 + m * 16 + (l & 15);
#pragma unroll
            for (int ks = 0; ks < 2; ++ks) {
                const int slot = (l >> 4) + ks * 4;
                af[m][ks] = *(const bf16x8s*)&sA[cur][(size_t)row * 64 + (slot ^ (row & 7)) * 8];
            }
        }
#pragma unroll
        for (int n = 0; n < 4; ++n) {
            const int row = wc * 64 + n * 16 + (l & 15);
#pragma unroll
            for (int ks = 0; ks < 2; ++ks) {
                const int slot = (l >> 4) + ks * 4;
                bfr[n][ks] = *(const bf16x8s*)&sB[cur][(size_t)row * 64 + (slot ^ (row & 7)) * 8];
            }
        }
#pragma unroll
        for (int ks = 0; ks < 2; ++ks)
#pragma unroll
            for (int m = 0; m < 2; ++m)
#pragma unroll
                for (int n = 0; n < 4; ++n)
                    acc[m][n] = __builtin_amdgcn_mfma_f32_16x16x32_bf16(af[m][ks], bfr[n][ks], acc[m][n], 0, 0, 0);
        __syncthreads();
    }
    if (bf16out) {
        ushort* Cb = (ushort*)Cp;
#pragma unroll
        for (int m = 0; m < 2; ++m) {
            const int row0 = brow + wr * 32 + m * 16 + (l >> 4) * 4;
#pragma unroll
            for (int n = 0; n < 4; ++n) {
                const int col = bcol + wc * 64 + n * 16 + (l & 15);
#pragma unroll
                for (int r = 0; r < 4; ++r)
                    Cb[(size_t)(row0 + r) * ldc + col] = f2bf(acc[m][n][r]);
            }
        }
    } else {
#pragma unroll
        for (int m = 0; m < 2; ++m) {
            const int row0 = brow + wr * 32 + m * 16 + (l >> 4) * 4;
#pragma unroll
            for (int n = 0; n < 4; ++n) {
                const int col = bcol + wc * 64 + n * 16 + (l & 15);
#pragma unroll
                for (int r = 0; r < 4; ++r)
                    Cp[(size_t)(row0 + r) * ldc + col] = acc[m][n][r];
            }
        }
    }
}

// ---------------- reduce 4 split-K partials (out-proj) ----------------------
__global__ __launch_bounds__(256) void reduce4(const float* __restrict__ p,
                                               float* __restrict__ outp) {
    const int i = blockIdx.x * 256 + threadIdx.x;
    float4 a = ((const float4*)p)[i];
    float4 b = ((const float4*)(p + 1048576))[i];
    float4 c = ((const float4*)(p + 2097152))[i];
    float4 d = ((const float4*)(p + 3145728))[i];
    float4 s;
    s.x = (a.x + b.x) + (c.x + d.x);
    s.y = (a.y + b.y) + (c.y + d.y);
    s.z = (a.z + b.z) + (c.z + d.z);
    s.w = (a.w + b.w) + (c.w + d.w);
    ((float4*)outp)[i] = s;
}

// ---------- per-(b,l) small ops (bf16 proj; skinny folded from pbuf) --------
__global__ __launch_bounds__(64) void small_ops(const ushort* __restrict__ projb,
                                                const float* __restrict__ pbuf,
                                                const float* __restrict__ dt_bias,
                                                const float* __restrict__ Bn_g,
                                                const float* __restrict__ Bn_b,
                                                const float* __restrict__ Cn_g,
                                                const float* __restrict__ Cn_b,
                                                float* __restrict__ DTa,
                                                float* __restrict__ deca,
                                                float* __restrict__ trpa,
                                                float* __restrict__ dtm,
                                                float* __restrict__ Bln,
                                                float* __restrict__ Cln) {
    const int bl = blockIdx.x;
    const int lane = threadIdx.x;
    const ushort* p = projb + (size_t)bl * DPROJ;

    float dt = 0.f;
    if (lane < NH_) {
        const size_t sb = (size_t)bl * 128 + lane;
        const float rdt = (pbuf[sb] + pbuf[PB + sb]) + (pbuf[2 * (size_t)PB + sb] + pbuf[3 * (size_t)PB + sb]);
        const float rda = (pbuf[sb + 32] + pbuf[PB + sb + 32]) + (pbuf[2 * (size_t)PB + sb + 32] + pbuf[3 * (size_t)PB + sb + 32]);
        const float rtr = (pbuf[sb + 64] + pbuf[PB + sb + 64]) + (pbuf[2 * (size_t)PB + sb + 64] + pbuf[3 * (size_t)PB + sb + 64]);
        dt = softplusf(rdt + dt_bias[lane]);
        DTa[bl * NH_ + lane] = dt;
        float a = -softplusf(rda);
        a = fminf(a, -1e-4f);
        deca[bl * NH_ + lane] = expf(a * dt);
        trpa[bl * NH_ + lane] = sigmoidf_(rtr);
    }
    float s = wave_sum(dt);
    if (lane == 0) dtm[bl] = s * (1.f / NH_);

    {
        float v = bf2f(p[OFF_BP + lane]);
        float m = wave_sum(v) * (1.f / 64.f);
        float d = v - m;
        float var = wave_sum(d * d) * (1.f / 64.f);
        Bln[bl * DS + lane] = d / sqrtf(var + 1e-5f) * Bn_g[lane] + Bn_b[lane];
    }
    {
        float v = bf2f(p[OFF_CP + lane]);
        float m = wave_sum(v) * (1.f / 64.f);
        float d = v - m;
        float var = wave_sum(d * d) * (1.f / 64.f);
        Cln[bl * DS + lane] = d / sqrtf(var + 1e-5f) * Cn_g[lane] + Cn_b[lane];
    }
}

// ---------- fused phase cumsum + RoPE (angles folded from pbuf) -------------
__global__ __launch_bounds__(64) void phase_rope(const float* __restrict__ pbuf,
                                                 const float* __restrict__ dtm,
                                                 const float* __restrict__ Bln,
                                                 const float* __restrict__ Cln,
                                                 float* __restrict__ Brot,
                                                 float* __restrict__ Crot) {
    const int b = blockIdx.x >> 5;
    const int a = blockIdx.x & 31;
    const int lane = threadIdx.x;
    float s[8];
    float run = 0.f;
#pragma unroll
    for (int j = 0; j < 8; ++j) {
        const int bl = b * L_ + lane * 8 + j;
        const size_t sb = (size_t)bl * 128 + 96 + a;
        const float ang = (pbuf[sb] + pbuf[PB + sb]) +
                          (pbuf[2 * (size_t)PB + sb] + pbuf[3 * (size_t)PB + sb]);
        run += ang * dtm[bl];
        s[j] = run;
    }
    float inc = run;
#pragma unroll
    for (int off = 1; off < 64; off <<= 1) {
        float v = __shfl_up(inc, off);
        if (lane >= off) inc += v;
    }
    const float excl = inc - run;
#pragma unroll
    for (int j = 0; j < 8; ++j) {
        const int bl = b * L_ + lane * 8 + j;
        const float ph = excl + s[j];
        float sn, cs;
        __sincosf(ph, &sn, &cs);
        {
            float ve = Bln[bl * DS + 2 * a], vo = Bln[bl * DS + 2 * a + 1];
            Brot[bl * DS + 2 * a]     = ve * cs - vo * sn;
            Brot[bl * DS + 2 * a + 1] = ve * sn + vo * cs;
        }
        {
            float ve = Cln[bl * DS + 2 * a], vo = Cln[bl * DS + 2 * a + 1];
            Crot[bl * DS + 2 * a]     = ve * cs - vo * sn;
            Crot[bl * DS + 2 * a + 1] = ve * sn + vo * cs;
        }
    }
}

// ---------- scan phase A: CHK=16, 2048 blocks (8/CU), f32 LDS tiles ---------
__global__ __launch_bounds__(256) void scanA(const ushort* __restrict__ projb,
                                             const float* __restrict__ Brot,
                                             const float* __restrict__ Crot,
                                             const float* __restrict__ DTa,
                                             const float* __restrict__ deca,
                                             const float* __restrict__ trpa,
                                             ushort* __restrict__ yactb,
                                             ushort* __restrict__ hendb) {
    __shared__ float Ball[CHK + 1][64];
    __shared__ float Call[CHK][64];
    __shared__ float Xall[CHK + 1][64];
    __shared__ float sa_[CHK], sb_[CHK], sdl[CHK];
    __shared__ float ypart[4][8][64];
    const int blk = blockIdx.x;
    const int c  = blk & 31;           // NCH=32 chunks
    const int bh = blk >> 5;
    const int h  = bh & 31;
    const int b  = bh >> 5;
    const int tid = threadIdx.x;
    const int lane = tid & 63;
    const int wv = tid >> 6;
    const int bl0 = b * L_ + c * CHK;

    if (wv == 0) {
        Ball[0][lane] = (c > 0) ? Brot[(bl0 - 1) * DS + lane] : 0.f;
        Xall[0][lane] = (c > 0) ? bf2f(projb[(size_t)(bl0 - 1) * DPROJ + OFF_X + h * HD + lane]) : 0.f;
    }
    for (int r = wv; r < CHK; r += 4) {
        Ball[r + 1][lane] = Brot[(bl0 + r) * DS + lane];
        Call[r][lane]     = Crot[(bl0 + r) * DS + lane];
        Xall[r + 1][lane] = bf2f(projb[(size_t)(bl0 + r) * DPROJ + OFF_X + h * HD + lane]);
    }
    if (tid < CHK) {
        float d  = deca[(bl0 + tid) * NH_ + h];
        float dt = DTa[(bl0 + tid) * NH_ + h];
        float te = trpa[(bl0 + tid) * NH_ + h];
        sdl[tid] = d;
        sa_[tid] = dt * te;
        sb_[tid] = dt * (1.f - te);
    }
    __syncthreads();

    float4 h4[4], bp[4];
#pragma unroll
    for (int q = 0; q < 4; ++q) {
        h4[q] = make_float4(0.f, 0.f, 0.f, 0.f);
        bp[q] = *(const float4*)&Ball[0][(wv * 4 + q) * 4];
    }
    float xp = Xall[0][lane];

#pragma unroll
    for (int qt = 0; qt < 2; ++qt) {   // CHK/8 = 2
#pragma unroll
        for (int i8 = 0; i8 < 8; ++i8) {
            const int i = qt * 8 + i8;
            const float xi = Xall[i + 1][lane];
            const float ac = sa_[i] * xi;
            const float bc = sb_[i] * xp;
            const float d  = sdl[i];
            float yi = 0.f;
#pragma unroll
            for (int q = 0; q < 4; ++q) {
                const float4 bb = *(const float4*)&Ball[i + 1][(wv * 4 + q) * 4];
                const float4 cc = *(const float4*)&Call[i][(wv * 4 + q) * 4];
                h4[q].x = fmaf(d, h4[q].x, fmaf(ac, bb.x, bc * bp[q].x));
                h4[q].y = fmaf(d, h4[q].y, fmaf(ac, bb.y, bc * bp[q].y));
                h4[q].z = fmaf(d, h4[q].z, fmaf(ac, bb.z, bc * bp[q].z));
                h4[q].w = fmaf(d, h4[q].w, fmaf(ac, bb.w, bc * bp[q].w));
                yi = fmaf(h4[q].x, cc.x, yi);
                yi = fmaf(h4[q].y, cc.y, yi);
                yi = fmaf(h4[q].z, cc.z, yi);
                yi = fmaf(h4[q].w, cc.w, yi);
                bp[q] = bb;
            }
            xp = xi;
            ypart[wv][i8][lane] = yi;
        }
        __syncthreads();
#pragma unroll
        for (int k = 0; k < 2; ++k) {
            const int il = wv * 2 + k;
            const float s = (ypart[0][il][lane] + ypart[1][il][lane]) +
                            (ypart[2][il][lane] + ypart[3][il][lane]);
            yactb[(size_t)(bl0 + qt * 8 + il) * DI + h * HD + lane] = f2bf(s);
        }
        __syncthreads();
    }
    const size_t hbase = (size_t)(bh * NCH + c) * 4096;
#pragma unroll
    for (int q = 0; q < 4; ++q) {
        const int n4 = wv * 4 + q;
        const size_t hb = hbase + (size_t)(n4 * 4) * 64 + lane;
        hendb[hb]       = f2bf(h4[q].x);
        hendb[hb + 64]  = f2bf(h4[q].y);
        hendb[hb + 128] = f2bf(h4[q].z);
        hendb[hb + 192] = f2bf(h4[q].w);
    }
}

// ---------- scan phase B: combine 32 chunk states (bf16 hend, f32 regs) -----
__global__ __launch_bounds__(256) void scanB(const float* __restrict__ deca,
                                             ushort* __restrict__ hendb) {
    __shared__ float Pl[NCH];
    const int bh = blockIdx.x >> 2;
    const int slice = blockIdx.x & 3;
    const int h = bh & 31, b = bh >> 5;
    const int tid = threadIdx.x;
    if (tid < NCH) {
        float p = 1.f;
        for (int j = 0; j < CHK; ++j)
            p *= deca[(b * L_ + tid * CHK + j) * NH_ + h];
        Pl[tid] = p;
    }
    __syncthreads();
    const size_t eoff = (size_t)slice * 1024 + tid * 4;
    const size_t cbase = (size_t)bh * NCH * 4096;
    float4 run = make_float4(0.f, 0.f, 0.f, 0.f);
    float4 cur = ld_bf4(&hendb[cbase + eoff]);
    float4 nx  = ld_bf4(&hendb[cbase + 4096 + eoff]);
    for (int cc = 0; cc < NCH - 1; ++cc) {
        float4 fut = make_float4(0.f, 0.f, 0.f, 0.f);
        if (cc + 2 <= NCH - 2)
            fut = ld_bf4(&hendb[cbase + (size_t)(cc + 2) * 4096 + eoff]);
        const float Pc = Pl[cc];
        run.x = fmaf(Pc, run.x, cur.x);
        run.y = fmaf(Pc, run.y, cur.y);
        run.z = fmaf(Pc, run.z, cur.z);
        run.w = fmaf(Pc, run.w, cur.w);
        st_bf4(&hendb[cbase + (size_t)cc * 4096 + eoff], run);
        cur = nx; nx = fut;
    }
}

// ---------- scan phase C: CHK=16, 2048 blocks, gate -> bf16 -----------------
__global__ __launch_bounds__(256) void scanC(const ushort* __restrict__ projb,
                                             const float* __restrict__ Crot,
                                             const float* __restrict__ deca,
                                             const ushort* __restrict__ hendb,
                                             const float* __restrict__ D_param,
                                             const ushort* __restrict__ yactb,
                                             ushort* __restrict__ ybf) {
    __shared__ float Call[CHK][64];
    __shared__ float sdl[CHK];
    __shared__ float wcum[CHK];
    __shared__ float cpart[4][16][64];
    const int blk = blockIdx.x;
    const int c = blk & 31;            // NCH=32
    const int bh = blk >> 5;
    const int h = bh & 31, b = bh >> 5;
    const int tid = threadIdx.x;
    const int lane = tid & 63;
    const int wv = tid >> 6;
    const int bl0 = b * L_ + c * CHK;

    for (int r = wv; r < CHK; r += 4)
        Call[r][lane] = Crot[(bl0 + r) * DS + lane];
    if (tid < CHK) sdl[tid] = deca[(bl0 + tid) * NH_ + h];

    float4 h0[4];
    if (c > 0) {
        const size_t base = (size_t)(bh * NCH + (c - 1)) * 4096;
#pragma unroll
        for (int q = 0; q < 4; ++q) {
            const int n4 = wv * 4 + q;
            h0[q].x = bf2f(hendb[base + (size_t)(n4 * 4 + 0) * 64 + lane]);
            h0[q].y = bf2f(hendb[base + (size_t)(n4 * 4 + 1) * 64 + lane]);
            h0[q].z = bf2f(hendb[base + (size_t)(n4 * 4 + 2) * 64 + lane]);
            h0[q].w = bf2f(hendb[base + (size_t)(n4 * 4 + 3) * 64 + lane]);
        }
    } else {
#pragma unroll
        for (int q = 0; q < 4; ++q) h0[q] = make_float4(0.f, 0.f, 0.f, 0.f);
    }
    __syncthreads();
    if (tid < CHK) {
        float p = 1.f;
        for (int k = 0; k <= tid; ++k) p *= sdl[k];
        wcum[tid] = p;
    }

    const float Dp = D_param[h];
#pragma unroll
    for (int i16 = 0; i16 < CHK; ++i16) {
        float s = 0.f;
#pragma unroll
        for (int q = 0; q < 4; ++q) {
            const float4 cc = *(const float4*)&Call[i16][(wv * 4 + q) * 4];
            s = fmaf(h0[q].x, cc.x, s);
            s = fmaf(h0[q].y, cc.y, s);
            s = fmaf(h0[q].z, cc.z, s);
            s = fmaf(h0[q].w, cc.w, s);
        }
        cpart[wv][i16][lane] = s;
    }
    __syncthreads();
#pragma unroll
    for (int k = 0; k < 4; ++k) {
        const int i = wv * 4 + k;
        const int bl = bl0 + i;
        const float s = (cpart[0][i][lane] + cpart[1][i][lane]) +
                        (cpart[2][i][lane] + cpart[3][i][lane]);
        const float xv = bf2f(projb[(size_t)bl * DPROJ + OFF_X + h * HD + lane]);
        const float zv = bf2f(projb[(size_t)bl * DPROJ + OFF_Z + h * HD + lane]);
        const float ya = bf2f(yactb[(size_t)bl * DI + h * HD + lane]);
        const float yv = ya + wcum[i] * s + Dp * xv;
        ybf[(size_t)bl * DI + h * HD + lane] = f2bf(yv * zv * sigmoidf_(zv));
    }
}

extern "C" void kernel_launch(void* const* d_in, const int* in_sizes, int n_in,
                              void* d_out, int out_size, void* d_ws, size_t ws_size,
                              hipStream_t stream) {
    const float* u       = (const float*)d_in[0];
    const float* W_in    = (const float*)d_in[1];
    const float* W_out   = (const float*)d_in[2];
    const float* dt_bias = (const float*)d_in[3];
    const float* D_param = (const float*)d_in[4];
    const float* Bn_g    = (const float*)d_in[5];
    const float* Bn_b    = (const float*)d_in[6];
    const float* Cn_g    = (const float*)d_in[7];
    const float* Cn_b    = (const float*)d_in[8];
    float* out = (float*)d_out;

    float* ws    = (float*)d_ws;
    float* proj  = ws;                          // bf16 proj: BL*DPROJ ushort (region over-sized)
    float* Bln   = proj + (size_t)BL * DIP;
    float* Cln   = Bln + BL * DS;
    float* Brot  = Cln + BL * DS;
    float* Crot  = Brot + BL * DS;
    float* DTa   = Crot + BL * DS;
    float* deca  = DTa + BL * NH_;
    float* trpa  = deca + BL * NH_;
    float* dtm   = trpa + BL * NH_;
    float* phase = dtm + BL;                    // BL*NA (reserved, unused)
    float* yact  = phase + BL * NA;             // region holds ubf then bf16 yact
    float* ybf_f = yact + (size_t)BL * DI;      // BL*DI bf16 (scanC output)
    float* wout_f= ybf_f + (size_t)BL * DI / 2; // WoutT bf16
    float* shreg = wout_f + (size_t)DM * DI / 2;// 4,194,304 f shared region
    float* pbuf  = shreg + 4194304;             // 4*BL*128 = 524,288 f

    // aliases
    ushort* projb = (ushort*)proj;              // bf16 proj, stride DPROJ
    ushort* ubf   = (ushort*)yact;              // in-proj A (dead before scanA writes)
    ushort* yactb = (ushort*)yact;              // bf16 yact (overlaps dead ubf)
    ushort* WinT  = (ushort*)shreg;             // in-proj B^T (dead before scanA's hend)
    ushort* hendb = (ushort*)shreg;             // bf16 hend: B*NH*NCH*4096 us = 16.7MB (fits shreg)
    float*  cpart = shreg;                      // out-proj partials (after scanC)
    ushort* WoutT = (ushort*)wout_f;
    ushort* ybf   = (ushort*)ybf_f;

    // 1) fused operand prep (transposes + u cast + skinny split-K)
    prep_all<<<dim3(1600 + 1024 + 1024), dim3(256), 0, stream>>>(
        u, W_in, W_out, ubf, WinT, WoutT, pbuf);
    // 2) in-projection: bf16 MFMA for cols 0..4224, bf16 output
    gemm_bf16<<<dim3(33, 16, 1), dim3(256), 0, stream>>>(ubf, WinT, proj, DM, DPROJ, DM,
                                                         0, 1);
    // 3) small per-(b,l) ops (folds skinny partials)
    small_ops<<<dim3(BL), dim3(64), 0, stream>>>(projb, pbuf, dt_bias, Bn_g, Bn_b, Cn_g, Cn_b,
                                                 DTa, deca, trpa, dtm, Bln, Cln);
    // 4) fused phase cumsum + RoPE (folds skinny partials)
    phase_rope<<<dim3(B_ * NA), dim3(64), 0, stream>>>(pbuf, dtm, Bln, Cln, Brot, Crot);
    // 5) chunked scan: CHK=16, NCH=32 -> 2048 blocks for scanA/scanC
    scanA<<<dim3(B_ * NH_ * NCH), dim3(256), 0, stream>>>(projb, Brot, Crot, DTa, deca, trpa,
                                                          yactb, hendb);
    scanB<<<dim3(B_ * NH_ * 4), dim3(256), 0, stream>>>(deca, hendb);
    scanC<<<dim3(B_ * NH_ * NCH), dim3(256), 0, stream>>>(projb, Crot, deca, hendb, D_param,
                                                          yactb, ybf);
    // 6) out-projection: bf16 MFMA, split-K=4, f32 partials, deterministic reduce
    gemm_bf16<<<dim3(8, 16, 4), dim3(256), 0, stream>>>(ybf, WoutT, cpart, DI, DM, DI / 4,
                                                        (size_t)BL * DM, 0);
    reduce4<<<dim3(1024), dim3(256), 0, stream>>>(cpart, out);
}

// Round 32
// 106.005 us; speedup vs baseline: 1.0364x; 1.0364x over previous
//
#include <hip/hip_runtime.h>
#include <hip/hip_bf16.h>
#include <math.h>

#define B_   2
#define L_   512
#define DM   1024
#define DIP  4352
#define DPROJ 4224        // bf16 proj row stride (Z,X,BP,CP only)
#define DI   2048
#define NH_  32
#define HD   64
#define DS   64
#define NA   32
#define BL   (B_ * L_)
#define CHK  32
#define NCH  16
#define PB   (BL * 128)   // one skinny partial plane

// proj slice offsets (within DPROJ-stride bf16 buffer)
#define OFF_Z    0
#define OFF_X    2048
#define OFF_BP   4096
#define OFF_CP   4160

typedef short bf16x8s __attribute__((ext_vector_type(8)));
typedef float f32x4 __attribute__((ext_vector_type(4)));

// async global->LDS, 16B/lane; LDS dest is wave-uniform base + lane*16 (HW).
#define GL2LDS(gp, lp) __builtin_amdgcn_global_load_lds( \
    (const __attribute__((address_space(1))) unsigned int*)(const void*)(gp), \
    (__attribute__((address_space(3))) unsigned int*)(void*)(lp), 16, 0, 0)

__device__ __forceinline__ float softplusf(float x) {
    return x > 0.f ? x + log1pf(expf(-x)) : log1pf(expf(x));
}
__device__ __forceinline__ float sigmoidf_(float x) {
    return 1.f / (1.f + expf(-x));
}
__device__ __forceinline__ float wave_sum(float v) {
#pragma unroll
    for (int off = 32; off; off >>= 1) v += __shfl_xor(v, off);
    return v;
}
__device__ __forceinline__ ushort f2bf(float f) {
    uint u = __float_as_uint(f);
    return (ushort)((u + 0x7fffu + ((u >> 16) & 1u)) >> 16);
}
__device__ __forceinline__ float bf2f(ushort v) {
    return __uint_as_float((uint)v << 16);
}
__device__ __forceinline__ float4 ld_bf4(const ushort* p) {
    uint2 v = *(const uint2*)p;
    float4 r;
    r.x = __uint_as_float(v.x << 16);
    r.y = __uint_as_float(v.x & 0xffff0000u);
    r.z = __uint_as_float(v.y << 16);
    r.w = __uint_as_float(v.y & 0xffff0000u);
    return r;
}
__device__ __forceinline__ void st_bf4(ushort* p, float4 f) {
    uint2 v;
    v.x = (uint)f2bf(f.x) | ((uint)f2bf(f.y) << 16);
    v.y = (uint)f2bf(f.z) | ((uint)f2bf(f.w) << 16);
    *(uint2*)p = v;
}

// ---------------- fused prep: W transposes + u cast + skinny split-K --------
__global__ __launch_bounds__(256) void prep_all(const float* __restrict__ u,
                                                const float* __restrict__ W_in,
                                                const float* __restrict__ W_out,
                                                ushort* __restrict__ ubf,
                                                ushort* __restrict__ WinT,
                                                ushort* __restrict__ WoutT,
                                                float* __restrict__ pbuf) {
    __shared__ float smem[2560];      // 10 KB, reinterpreted per role
    const int blk = blockIdx.x;
    const int tid = threadIdx.x;

    if (blk < 1600) {                 // ---- transpose roles ----
        ushort (*t2)[72] = (ushort(*)[72])smem;   // [64][72] = 9216 B
        const float* in;
        ushort* outp;
        int R, C, c0, r0;
        if (blk < 1088) {
            in = W_in; outp = WinT; R = DM; C = DIP;
            c0 = (blk % 68) * 64; r0 = (blk / 68) * 64;
        } else {
            const int bi = blk - 1088;
            in = W_out; outp = WoutT; R = DI; C = DM;
            c0 = (bi % 16) * 64; r0 = (bi / 16) * 64;
        }
        const int cq = tid & 15;
        const int rrb = tid >> 4;
#pragma unroll
        for (int j = 0; j < 4; ++j) {
            const int rr = j * 16 + rrb;
            float4 v = *(const float4*)&in[(size_t)(r0 + rr) * C + c0 + cq * 4];
            uint u0 = (uint)f2bf(v.x) | ((uint)f2bf(v.y) << 16);
            uint u1 = (uint)f2bf(v.z) | ((uint)f2bf(v.w) << 16);
            const int g = cq ^ ((rr >> 3) & 3);
            *(uint2*)&t2[rr][g * 4] = make_uint2(u0, u1);
        }
        __syncthreads();
        const int rq = tid & 7;
        const int ccb = tid >> 3;
#pragma unroll
        for (int j = 0; j < 2; ++j) {
            const int cc = j * 32 + ccb;
            ushort a[8];
#pragma unroll
            for (int i = 0; i < 8; ++i) {
                const int r = rq * 8 + i;
                const int g = (cc >> 2) ^ ((r >> 3) & 3);
                a[i] = t2[r][g * 4 + (cc & 3)];
            }
            uint4 w;
            w.x = (uint)a[0] | ((uint)a[1] << 16);
            w.y = (uint)a[2] | ((uint)a[3] << 16);
            w.z = (uint)a[4] | ((uint)a[5] << 16);
            w.w = (uint)a[6] | ((uint)a[7] << 16);
            *(uint4*)&outp[(size_t)(c0 + cc) * R + r0 + rq * 8] = w;
        }
        return;
    }
    if (blk < 2624) {                 // ---- u cast role ----
        const int i = (blk - 1600) * 256 + tid;
        float4 v = ((const float4*)u)[i];
        uint u0 = (uint)f2bf(v.x) | ((uint)f2bf(v.y) << 16);
        uint u1 = (uint)f2bf(v.z) | ((uint)f2bf(v.w) << 16);
        *(uint2*)&ubf[(size_t)i * 4] = make_uint2(u0, u1);
        return;
    }
    // ---- skinny split-K role ----
    float (*us)[256] = (float(*)[256])smem;       // 4 x 256 f = 4 KB
    float* part = smem + 1024;                    // 4 x 256 f = 4 KB
    const int sblk = blk - 2624;
    const int rb = sblk & 255;
    const int ks = sblk >> 8;
    const int blr = rb * 4;
    const int k0 = ks * 256;
    {
        const int r = tid >> 6, s = tid & 63;
        *(float4*)&us[r][s * 4] = *(const float4*)&u[(size_t)(blr + r) * DM + k0 + s * 4];
    }
    __syncthreads();
    const int col = tid & 127;
    const int half = tid >> 7;
    float s0 = 0.f, s1 = 0.f, s2 = 0.f, s3 = 0.f;
    const float* wp = W_in + (size_t)(k0 + half * 128) * DIP + 4224 + col;
#pragma unroll 16
    for (int k = 0; k < 128; ++k) {
        const float wv = wp[(size_t)k * DIP];
        s0 = fmaf(us[0][half * 128 + k], wv, s0);
        s1 = fmaf(us[1][half * 128 + k], wv, s1);
        s2 = fmaf(us[2][half * 128 + k], wv, s2);
        s3 = fmaf(us[3][half * 128 + k], wv, s3);
    }
    part[0 * 256 + tid] = s0; part[1 * 256 + tid] = s1;
    part[2 * 256 + tid] = s2; part[3 * 256 + tid] = s3;
    __syncthreads();
    if (tid < 128) {
#pragma unroll
        for (int r = 0; r < 4; ++r)
            pbuf[((size_t)ks * BL + blr + r) * 128 + tid] =
                part[r * 256 + tid] + part[r * 256 + 128 + tid];
    }
}

// ---------------- bf16 MFMA GEMM: C[M,N] = A[M,K] @ BT[N,K] -----------------
__global__ __launch_bounds__(256) void gemm_bf16(const ushort* __restrict__ A,
                                                 const ushort* __restrict__ BT,
                                                 float* __restrict__ C,
                                                 int K, int ldc, int kslice,
                                                 size_t partStride, int bf16out) {
    __shared__ ushort sA[2][64 * 64];     // 2 x 8 KB
    __shared__ ushort sB[2][128 * 64];    // 2 x 16 KB
    const int tid = threadIdx.x;
    const int l = tid & 63;
    const int wv = tid >> 6;
    const int wr = wv >> 1, wc = wv & 1;
    const int brow = blockIdx.y * 64;
    const int bcol = blockIdx.x * 128;
    const int kstart = blockIdx.z * kslice;
    float* Cp = C + (size_t)blockIdx.z * partStride;

    const int rr8 = l >> 3;           // 0..7
    const int swz = ((l & 7) ^ rr8) * 8;   // pre-swizzled source slot (ushort)

    const ushort* gA0 = A + (size_t)(brow + wv * 16 + 0 + rr8) * K + kstart + swz;
    const ushort* gA1 = A + (size_t)(brow + wv * 16 + 8 + rr8) * K + kstart + swz;
    const ushort* gB0 = BT + (size_t)(bcol + wv * 32 + 0 + rr8) * K + kstart + swz;
    const ushort* gB1 = BT + (size_t)(bcol + wv * 32 + 8 + rr8) * K + kstart + swz;
    const ushort* gB2 = BT + (size_t)(bcol + wv * 32 + 16 + rr8) * K + kstart + swz;
    const ushort* gB3 = BT + (size_t)(bcol + wv * 32 + 24 + rr8) * K + kstart + swz;

    f32x4 acc[2][4] = {};

    GL2LDS(gA0, &sA[0][(wv * 16 + 0) * 64]);
    GL2LDS(gA1, &sA[0][(wv * 16 + 8) * 64]);
    GL2LDS(gB0, &sB[0][(wv * 32 + 0) * 64]);
    GL2LDS(gB1, &sB[0][(wv * 32 + 8) * 64]);
    GL2LDS(gB2, &sB[0][(wv * 32 + 16) * 64]);
    GL2LDS(gB3, &sB[0][(wv * 32 + 24) * 64]);
    __syncthreads();

    for (int k0 = 0; k0 < kslice; k0 += 64) {
        const int cur = (k0 >> 6) & 1;
        const int nxt = cur ^ 1;
        if (k0 + 64 < kslice) {
            GL2LDS(gA0 + k0 + 64, &sA[nxt][(wv * 16 + 0) * 64]);
            GL2LDS(gA1 + k0 + 64, &sA[nxt][(wv * 16 + 8) * 64]);
            GL2LDS(gB0 + k0 + 64, &sB[nxt][(wv * 32 + 0) * 64]);
            GL2LDS(gB1 + k0 + 64, &sB[nxt][(wv * 32 + 8) * 64]);
            GL2LDS(gB2 + k0 + 64, &sB[nxt][(wv * 32 + 16) * 64]);
            GL2LDS(gB3 + k0 + 64, &sB[nxt][(wv * 32 + 24) * 64]);
        }
        bf16x8s af[2][2], bfr[4][2];
#pragma unroll
        for (int m = 0; m < 2; ++m) {
            const int row = wr * 32 + m * 16 + (l & 15);
#pragma unroll
            for (int ks = 0; ks < 2; ++ks) {
                const int slot = (l >> 4) + ks * 4;
                af[m][ks] = *(const bf16x8s*)&sA[cur][(size_t)row * 64 + (slot ^ (row & 7)) * 8];
            }
        }
#pragma unroll
        for (int n = 0; n < 4; ++n) {
            const int row = wc * 64 + n * 16 + (l & 15);
#pragma unroll
            for (int ks = 0; ks < 2; ++ks) {
                const int slot = (l >> 4) + ks * 4;
                bfr[n][ks] = *(const bf16x8s*)&sB[cur][(size_t)row * 64 + (slot ^ (row & 7)) * 8];
            }
        }
#pragma unroll
        for (int ks = 0; ks < 2; ++ks)
#pragma unroll
            for (int m = 0; m < 2; ++m)
#pragma unroll
                for (int n = 0; n < 4; ++n)
                    acc[m][n] = __builtin_amdgcn_mfma_f32_16x16x32_bf16(af[m][ks], bfr[n][ks], acc[m][n], 0, 0, 0);
        __syncthreads();
    }
    if (bf16out) {
        ushort* Cb = (ushort*)Cp;
#pragma unroll
        for (int m = 0; m < 2; ++m) {
            const int row0 = brow + wr * 32 + m * 16 + (l >> 4) * 4;
#pragma unroll
            for (int n = 0; n < 4; ++n) {
                const int col = bcol + wc * 64 + n * 16 + (l & 15);
#pragma unroll
                for (int r = 0; r < 4; ++r)
                    Cb[(size_t)(row0 + r) * ldc + col] = f2bf(acc[m][n][r]);
            }
        }
    } else {
#pragma unroll
        for (int m = 0; m < 2; ++m) {
            const int row0 = brow + wr * 32 + m * 16 + (l >> 4) * 4;
#pragma unroll
            for (int n = 0; n < 4; ++n) {
                const int col = bcol + wc * 64 + n * 16 + (l & 15);
#pragma unroll
                for (int r = 0; r < 4; ++r)
                    Cp[(size_t)(row0 + r) * ldc + col] = acc[m][n][r];
            }
        }
    }
}

// ---------------- reduce 4 split-K partials (out-proj) ----------------------
__global__ __launch_bounds__(256) void reduce4(const float* __restrict__ p,
                                               float* __restrict__ outp) {
    const int i = blockIdx.x * 256 + threadIdx.x;
    float4 a = ((const float4*)p)[i];
    float4 b = ((const float4*)(p + 1048576))[i];
    float4 c = ((const float4*)(p + 2097152))[i];
    float4 d = ((const float4*)(p + 3145728))[i];
    float4 s;
    s.x = (a.x + b.x) + (c.x + d.x);
    s.y = (a.y + b.y) + (c.y + d.y);
    s.z = (a.z + b.z) + (c.z + d.z);
    s.w = (a.w + b.w) + (c.w + d.w);
    ((float4*)outp)[i] = s;
}

// ---------- per-(b,l) small ops (bf16 proj; skinny folded from pbuf) --------
__global__ __launch_bounds__(64) void small_ops(const ushort* __restrict__ projb,
                                                const float* __restrict__ pbuf,
                                                const float* __restrict__ dt_bias,
                                                const float* __restrict__ Bn_g,
                                                const float* __restrict__ Bn_b,
                                                const float* __restrict__ Cn_g,
                                                const float* __restrict__ Cn_b,
                                                float* __restrict__ DTa,
                                                float* __restrict__ deca,
                                                float* __restrict__ trpa,
                                                float* __restrict__ dtm,
                                                float* __restrict__ Bln,
                                                float* __restrict__ Cln) {
    const int bl = blockIdx.x;
    const int lane = threadIdx.x;
    const ushort* p = projb + (size_t)bl * DPROJ;

    float dt = 0.f;
    if (lane < NH_) {
        const size_t sb = (size_t)bl * 128 + lane;
        const float rdt = (pbuf[sb] + pbuf[PB + sb]) + (pbuf[2 * (size_t)PB + sb] + pbuf[3 * (size_t)PB + sb]);
        const float rda = (pbuf[sb + 32] + pbuf[PB + sb + 32]) + (pbuf[2 * (size_t)PB + sb + 32] + pbuf[3 * (size_t)PB + sb + 32]);
        const float rtr = (pbuf[sb + 64] + pbuf[PB + sb + 64]) + (pbuf[2 * (size_t)PB + sb + 64] + pbuf[3 * (size_t)PB + sb + 64]);
        dt = softplusf(rdt + dt_bias[lane]);
        DTa[bl * NH_ + lane] = dt;
        float a = -softplusf(rda);
        a = fminf(a, -1e-4f);
        deca[bl * NH_ + lane] = expf(a * dt);
        trpa[bl * NH_ + lane] = sigmoidf_(rtr);
    }
    float s = wave_sum(dt);
    if (lane == 0) dtm[bl] = s * (1.f / NH_);

    {
        float v = bf2f(p[OFF_BP + lane]);
        float m = wave_sum(v) * (1.f / 64.f);
        float d = v - m;
        float var = wave_sum(d * d) * (1.f / 64.f);
        Bln[bl * DS + lane] = d / sqrtf(var + 1e-5f) * Bn_g[lane] + Bn_b[lane];
    }
    {
        float v = bf2f(p[OFF_CP + lane]);
        float m = wave_sum(v) * (1.f / 64.f);
        float d = v - m;
        float var = wave_sum(d * d) * (1.f / 64.f);
        Cln[bl * DS + lane] = d / sqrtf(var + 1e-5f) * Cn_g[lane] + Cn_b[lane];
    }
}

// ---------- fused phase cumsum + RoPE (angles folded from pbuf) -------------
__global__ __launch_bounds__(64) void phase_rope(const float* __restrict__ pbuf,
                                                 const float* __restrict__ dtm,
                                                 const float* __restrict__ Bln,
                                                 const float* __restrict__ Cln,
                                                 float* __restrict__ Brot,
                                                 float* __restrict__ Crot) {
    const int b = blockIdx.x >> 5;
    const int a = blockIdx.x & 31;
    const int lane = threadIdx.x;
    float s[8];
    float run = 0.f;
#pragma unroll
    for (int j = 0; j < 8; ++j) {
        const int bl = b * L_ + lane * 8 + j;
        const size_t sb = (size_t)bl * 128 + 96 + a;
        const float ang = (pbuf[sb] + pbuf[PB + sb]) +
                          (pbuf[2 * (size_t)PB + sb] + pbuf[3 * (size_t)PB + sb]);
        run += ang * dtm[bl];
        s[j] = run;
    }
    float inc = run;
#pragma unroll
    for (int off = 1; off < 64; off <<= 1) {
        float v = __shfl_up(inc, off);
        if (lane >= off) inc += v;
    }
    const float excl = inc - run;
#pragma unroll
    for (int j = 0; j < 8; ++j) {
        const int bl = b * L_ + lane * 8 + j;
        const float ph = excl + s[j];
        float sn, cs;
        __sincosf(ph, &sn, &cs);
        {
            float ve = Bln[bl * DS + 2 * a], vo = Bln[bl * DS + 2 * a + 1];
            Brot[bl * DS + 2 * a]     = ve * cs - vo * sn;
            Brot[bl * DS + 2 * a + 1] = ve * sn + vo * cs;
        }
        {
            float ve = Cln[bl * DS + 2 * a], vo = Cln[bl * DS + 2 * a + 1];
            Crot[bl * DS + 2 * a]     = ve * cs - vo * sn;
            Crot[bl * DS + 2 * a + 1] = ve * sn + vo * cs;
        }
    }
}

// ---------- scan phase A: 8 waves/block (512 thr), 2 q/wave, 4 blk/CU -------
__global__ __launch_bounds__(512, 8) void scanA(const ushort* __restrict__ projb,
                                                const float* __restrict__ Brot,
                                                const float* __restrict__ Crot,
                                                const float* __restrict__ DTa,
                                                const float* __restrict__ deca,
                                                const float* __restrict__ trpa,
                                                ushort* __restrict__ yactb,
                                                ushort* __restrict__ hendb) {
    __shared__ float Ball[CHK + 1][64];     // 8448 B
    __shared__ float Call[CHK][64];         // 8192 B
    __shared__ float Xall[CHK + 1][64];     // 8448 B
    __shared__ float sa_[CHK], sb_[CHK], sdl[CHK];
    __shared__ float ypart[8][4][64];       // 8192 B
    const int blk = blockIdx.x;
    const int c  = blk & 15;
    const int bh = blk >> 4;
    const int h  = bh & 31;
    const int b  = bh >> 5;
    const int tid = threadIdx.x;
    const int lane = tid & 63;
    const int wv = tid >> 6;               // 0..7
    const int bl0 = b * L_ + c * CHK;

    if (wv == 0) {
        Ball[0][lane] = (c > 0) ? Brot[(bl0 - 1) * DS + lane] : 0.f;
        Xall[0][lane] = (c > 0) ? bf2f(projb[(size_t)(bl0 - 1) * DPROJ + OFF_X + h * HD + lane]) : 0.f;
    }
    for (int r = wv; r < CHK; r += 8) {
        Ball[r + 1][lane] = Brot[(bl0 + r) * DS + lane];
        Call[r][lane]     = Crot[(bl0 + r) * DS + lane];
        Xall[r + 1][lane] = bf2f(projb[(size_t)(bl0 + r) * DPROJ + OFF_X + h * HD + lane]);
    }
    if (tid < CHK) {
        float d  = deca[(bl0 + tid) * NH_ + h];
        float dt = DTa[(bl0 + tid) * NH_ + h];
        float te = trpa[(bl0 + tid) * NH_ + h];
        sdl[tid] = d;
        sa_[tid] = dt * te;
        sb_[tid] = dt * (1.f - te);
    }
    __syncthreads();

    float4 h4[2], bp[2];
#pragma unroll
    for (int q = 0; q < 2; ++q) {
        h4[q] = make_float4(0.f, 0.f, 0.f, 0.f);
        bp[q] = *(const float4*)&Ball[0][(wv * 2 + q) * 4];
    }
    float xp = Xall[0][lane];

#pragma unroll
    for (int qt = 0; qt < 8; ++qt) {       // 8 rounds of 4 timesteps
#pragma unroll
        for (int i8 = 0; i8 < 4; ++i8) {
            const int i = qt * 4 + i8;
            const float xi = Xall[i + 1][lane];
            const float ac = sa_[i] * xi;
            const float bc = sb_[i] * xp;
            const float d  = sdl[i];
            float yi = 0.f;
#pragma unroll
            for (int q = 0; q < 2; ++q) {
                const float4 bb = *(const float4*)&Ball[i + 1][(wv * 2 + q) * 4];
                const float4 cc = *(const float4*)&Call[i][(wv * 2 + q) * 4];
                h4[q].x = fmaf(d, h4[q].x, fmaf(ac, bb.x, bc * bp[q].x));
                h4[q].y = fmaf(d, h4[q].y, fmaf(ac, bb.y, bc * bp[q].y));
                h4[q].z = fmaf(d, h4[q].z, fmaf(ac, bb.z, bc * bp[q].z));
                h4[q].w = fmaf(d, h4[q].w, fmaf(ac, bb.w, bc * bp[q].w));
                yi = fmaf(h4[q].x, cc.x, yi);
                yi = fmaf(h4[q].y, cc.y, yi);
                yi = fmaf(h4[q].z, cc.z, yi);
                yi = fmaf(h4[q].w, cc.w, yi);
                bp[q] = bb;
            }
            xp = xi;
            ypart[wv][i8][lane] = yi;
        }
        __syncthreads();
        if (wv < 4) {
            const int il = wv;
            const float s = ((ypart[0][il][lane] + ypart[1][il][lane]) +
                             (ypart[2][il][lane] + ypart[3][il][lane])) +
                            ((ypart[4][il][lane] + ypart[5][il][lane]) +
                             (ypart[6][il][lane] + ypart[7][il][lane]));
            yactb[(size_t)(bl0 + qt * 4 + il) * DI + h * HD + lane] = f2bf(s);
        }
        __syncthreads();
    }
    const size_t hbase = (size_t)(bh * NCH + c) * 4096;
#pragma unroll
    for (int q = 0; q < 2; ++q) {
        const int n4 = wv * 2 + q;
        const size_t hb = hbase + (size_t)(n4 * 4) * 64 + lane;
        hendb[hb]       = f2bf(h4[q].x);
        hendb[hb + 64]  = f2bf(h4[q].y);
        hendb[hb + 128] = f2bf(h4[q].z);
        hendb[hb + 192] = f2bf(h4[q].w);
    }
}

// ---------- scan phase B: combine chunk states (bf16 hend, f32 registers) ---
__global__ __launch_bounds__(256) void scanB(const float* __restrict__ deca,
                                             ushort* __restrict__ hendb) {
    __shared__ float Pl[NCH];
    const int bh = blockIdx.x >> 2;
    const int slice = blockIdx.x & 3;
    const int h = bh & 31, b = bh >> 5;
    const int tid = threadIdx.x;
    if (tid < NCH) {
        float p = 1.f;
        for (int j = 0; j < CHK; ++j)
            p *= deca[(b * L_ + tid * CHK + j) * NH_ + h];
        Pl[tid] = p;
    }
    __syncthreads();
    const size_t eoff = (size_t)slice * 1024 + tid * 4;
    const size_t cbase = (size_t)bh * NCH * 4096;
    float4 run = make_float4(0.f, 0.f, 0.f, 0.f);
    float4 cur = ld_bf4(&hendb[cbase + eoff]);
    float4 nx  = ld_bf4(&hendb[cbase + 4096 + eoff]);
    for (int cc = 0; cc < NCH - 1; ++cc) {
        float4 fut = make_float4(0.f, 0.f, 0.f, 0.f);
        if (cc + 2 <= NCH - 2)
            fut = ld_bf4(&hendb[cbase + (size_t)(cc + 2) * 4096 + eoff]);
        const float Pc = Pl[cc];
        run.x = fmaf(Pc, run.x, cur.x);
        run.y = fmaf(Pc, run.y, cur.y);
        run.z = fmaf(Pc, run.z, cur.z);
        run.w = fmaf(Pc, run.w, cur.w);
        st_bf4(&hendb[cbase + (size_t)cc * 4096 + eoff], run);
        cur = nx; nx = fut;
    }
}

// ---------- scan phase C: 4 waves/block, gate -> bf16 (bf16 inputs) ---------
__global__ __launch_bounds__(256) void scanC(const ushort* __restrict__ projb,
                                             const float* __restrict__ Crot,
                                             const float* __restrict__ deca,
                                             const ushort* __restrict__ hendb,
                                             const float* __restrict__ D_param,
                                             const ushort* __restrict__ yactb,
                                             ushort* __restrict__ ybf) {
    __shared__ float Call[CHK][64];
    __shared__ float sdl[CHK];
    __shared__ float wcum[CHK];
    __shared__ float cpart[4][16][64];
    const int blk = blockIdx.x;
    const int c = blk & 15;
    const int bh = blk >> 4;
    const int h = bh & 31, b = bh >> 5;
    const int tid = threadIdx.x;
    const int lane = tid & 63;
    const int wv = tid >> 6;
    const int bl0 = b * L_ + c * CHK;

    for (int r = wv; r < CHK; r += 4)
        Call[r][lane] = Crot[(bl0 + r) * DS + lane];
    if (tid < CHK) sdl[tid] = deca[(bl0 + tid) * NH_ + h];

    float4 h0[4];
    if (c > 0) {
        const size_t base = (size_t)(bh * NCH + (c - 1)) * 4096;
#pragma unroll
        for (int q = 0; q < 4; ++q) {
            const int n4 = wv * 4 + q;
            h0[q].x = bf2f(hendb[base + (size_t)(n4 * 4 + 0) * 64 + lane]);
            h0[q].y = bf2f(hendb[base + (size_t)(n4 * 4 + 1) * 64 + lane]);
            h0[q].z = bf2f(hendb[base + (size_t)(n4 * 4 + 2) * 64 + lane]);
            h0[q].w = bf2f(hendb[base + (size_t)(n4 * 4 + 3) * 64 + lane]);
        }
    } else {
#pragma unroll
        for (int q = 0; q < 4; ++q) h0[q] = make_float4(0.f, 0.f, 0.f, 0.f);
    }
    __syncthreads();
    if (tid < CHK) {
        float p = 1.f;
        for (int k = 0; k <= tid; ++k) p *= sdl[k];
        wcum[tid] = p;
    }

    const float Dp = D_param[h];
#pragma unroll
    for (int half = 0; half < 2; ++half) {
#pragma unroll
        for (int i16 = 0; i16 < 16; ++i16) {
            const int i = half * 16 + i16;
            float s = 0.f;
#pragma unroll
            for (int q = 0; q < 4; ++q) {
                const float4 cc = *(const float4*)&Call[i][(wv * 4 + q) * 4];
                s = fmaf(h0[q].x, cc.x, s);
                s = fmaf(h0[q].y, cc.y, s);
                s = fmaf(h0[q].z, cc.z, s);
                s = fmaf(h0[q].w, cc.w, s);
            }
            cpart[wv][i16][lane] = s;
        }
        __syncthreads();
#pragma unroll
        for (int k = 0; k < 4; ++k) {
            const int il = wv * 4 + k;
            const int i  = half * 16 + il;
            const int bl = bl0 + i;
            const float s = (cpart[0][il][lane] + cpart[1][il][lane]) +
                            (cpart[2][il][lane] + cpart[3][il][lane]);
            const float xv = bf2f(projb[(size_t)bl * DPROJ + OFF_X + h * HD + lane]);
            const float zv = bf2f(projb[(size_t)bl * DPROJ + OFF_Z + h * HD + lane]);
            const float ya = bf2f(yactb[(size_t)bl * DI + h * HD + lane]);
            const float yv = ya + wcum[i] * s + Dp * xv;
            ybf[(size_t)bl * DI + h * HD + lane] = f2bf(yv * zv * sigmoidf_(zv));
        }
        __syncthreads();
    }
}

extern "C" void kernel_launch(void* const* d_in, const int* in_sizes, int n_in,
                              void* d_out, int out_size, void* d_ws, size_t ws_size,
                              hipStream_t stream) {
    const float* u       = (const float*)d_in[0];
    const float* W_in    = (const float*)d_in[1];
    const float* W_out   = (const float*)d_in[2];
    const float* dt_bias = (const float*)d_in[3];
    const float* D_param = (const float*)d_in[4];
    const float* Bn_g    = (const float*)d_in[5];
    const float* Bn_b    = (const float*)d_in[6];
    const float* Cn_g    = (const float*)d_in[7];
    const float* Cn_b    = (const float*)d_in[8];
    float* out = (float*)d_out;

    float* ws    = (float*)d_ws;
    float* proj  = ws;                          // bf16 proj: BL*DPROJ ushort (region over-sized)
    float* Bln   = proj + (size_t)BL * DIP;
    float* Cln   = Bln + BL * DS;
    float* Brot  = Cln + BL * DS;
    float* Crot  = Brot + BL * DS;
    float* DTa   = Crot + BL * DS;
    float* deca  = DTa + BL * NH_;
    float* trpa  = deca + BL * NH_;
    float* dtm   = trpa + BL * NH_;
    float* phase = dtm + BL;                    // BL*NA (reserved, unused)
    float* yact  = phase + BL * NA;             // region holds ubf then bf16 yact
    float* ybf_f = yact + (size_t)BL * DI;      // BL*DI bf16 (scanC output)
    float* wout_f= ybf_f + (size_t)BL * DI / 2; // WoutT bf16
    float* shreg = wout_f + (size_t)DM * DI / 2;// 4,194,304 f shared region
    float* pbuf  = shreg + 4194304;             // 4*BL*128 = 524,288 f

    // aliases
    ushort* projb = (ushort*)proj;              // bf16 proj, stride DPROJ
    ushort* ubf   = (ushort*)yact;              // in-proj A (dead before scanA writes)
    ushort* yactb = (ushort*)yact;              // bf16 yact (overlaps dead ubf)
    ushort* WinT  = (ushort*)shreg;             // in-proj B^T (dead before scanA's hend)
    ushort* hendb = (ushort*)shreg;             // bf16 hend (overlaps dead WinT)
    float*  cpart = shreg;                      // out-proj partials (after scanC)
    ushort* WoutT = (ushort*)wout_f;
    ushort* ybf   = (ushort*)ybf_f;

    // 1) fused operand prep (transposes + u cast + skinny split-K)
    prep_all<<<dim3(1600 + 1024 + 1024), dim3(256), 0, stream>>>(
        u, W_in, W_out, ubf, WinT, WoutT, pbuf);
    // 2) in-projection: bf16 MFMA for cols 0..4224, bf16 output
    gemm_bf16<<<dim3(33, 16, 1), dim3(256), 0, stream>>>(ubf, WinT, proj, DM, DPROJ, DM,
                                                         0, 1);
    // 3) small per-(b,l) ops (folds skinny partials)
    small_ops<<<dim3(BL), dim3(64), 0, stream>>>(projb, pbuf, dt_bias, Bn_g, Bn_b, Cn_g, Cn_b,
                                                 DTa, deca, trpa, dtm, Bln, Cln);
    // 4) fused phase cumsum + RoPE (folds skinny partials)
    phase_rope<<<dim3(B_ * NA), dim3(64), 0, stream>>>(pbuf, dtm, Bln, Cln, Brot, Crot);
    // 5) chunked scan (8-wave scanA for 2x occupancy; bf16 yact/hend)
    scanA<<<dim3(B_ * NH_ * NCH), dim3(512), 0, stream>>>(projb, Brot, Crot, DTa, deca, trpa,
                                                          yactb, hendb);
    scanB<<<dim3(B_ * NH_ * 4), dim3(256), 0, stream>>>(deca, hendb);
    scanC<<<dim3(B_ * NH_ * NCH), dim3(256), 0, stream>>>(projb, Crot, deca, hendb, D_param,
                                                          yactb, ybf);
    // 6) out-projection: bf16 MFMA, split-K=4, f32 partials, deterministic reduce
    gemm_bf16<<<dim3(8, 16, 4), dim3(256), 0, stream>>>(ybf, WoutT, cpart, DI, DM, DI / 4,
                                                        (size_t)BL * DM, 0);
    reduce4<<<dim3(1024), dim3(256), 0, stream>>>(cpart, out);
}